// Round 1
// baseline (766.092 us; speedup 1.0000x reference)
//
#include <hip/hip_runtime.h>
#include <hip/hip_bf16.h>

#define S_IMG 16384
#define N_TXT 4096
#define DIM   512
#define KDIM  512

typedef __attribute__((ext_vector_type(8))) short bf16x8;
typedef __attribute__((ext_vector_type(4))) float f32x4;

__device__ __forceinline__ short f2bf(float f) {
  unsigned u = __float_as_uint(f);
  u += 0x7FFFu + ((u >> 16) & 1u);   // RNE
  return (short)(u >> 16);
}

__device__ __forceinline__ float softplus_f(float x) {
  return fmaxf(x, 0.0f) + log1pf(expf(-fabsf(x)));
}

// ---------------- init: sentinel for segment-min, zero the loss accumulator ----
__global__ __launch_bounds__(256) void init_kernel(
    unsigned long long* __restrict__ packed, float* __restrict__ out_loss) {
  const int i = blockIdx.x * 256 + threadIdx.x;
  packed[i] = 0xFFFFFFFFFFFFFFFFull;
  if (i == 0) out_loss[0] = 0.0f;
}

// ---------------- L2 normalize rows (txt), emit f32 (output) + bf16 (MFMA) ----
__global__ __launch_bounds__(256) void normalize_kernel(
    const float* __restrict__ in, float* __restrict__ outf,
    short* __restrict__ outb) {
  const int w = threadIdx.x >> 6, l = threadIdx.x & 63;
  const size_t row = (size_t)blockIdx.x * 4 + w;
  const float4* r4 = (const float4*)(in + row * DIM);
  float4 a = r4[l], b = r4[l + 64];
  float s = a.x*a.x + a.y*a.y + a.z*a.z + a.w*a.w
          + b.x*b.x + b.y*b.y + b.z*b.z + b.w*b.w;
#pragma unroll
  for (int off = 32; off; off >>= 1) s += __shfl_xor(s, off, 64);
  const float inv = 1.0f / (sqrtf(s) + 1e-12f);
  a.x *= inv; a.y *= inv; a.z *= inv; a.w *= inv;
  b.x *= inv; b.y *= inv; b.z *= inv; b.w *= inv;
  float4* o4 = (float4*)(outf + row * DIM);
  o4[l] = a; o4[l + 64] = b;
  int2 pa, pb;
  pa.x = (f2bf(a.x) & 0xFFFF) | ((int)f2bf(a.y) << 16);
  pa.y = (f2bf(a.z) & 0xFFFF) | ((int)f2bf(a.w) << 16);
  pb.x = (f2bf(b.x) & 0xFFFF) | ((int)f2bf(b.y) << 16);
  pb.y = (f2bf(b.z) & 0xFFFF) | ((int)f2bf(b.w) << 16);
  ((int2*)(outb + row * DIM))[l]       = pa;
  ((int2*)(outb + row * DIM + 256))[l] = pb;
}

// ---------------- normalize img rows + FUSED exact-f32 tp logit + seg-min -----
// Fusion saves a full 33.5 MB re-read of zimg f32. The dot uses the identical
// expression tree as the old tp_select kernel (same values, same contraction)
// so the packed (loss,index) argmin selection is bit-stable vs the reference.
__global__ __launch_bounds__(256) void normalize_img_tp_kernel(
    const float* __restrict__ in, float* __restrict__ outf,
    short* __restrict__ outb, const float* __restrict__ ztxt,
    const int* __restrict__ key, unsigned long long* __restrict__ packed,
    const float* __restrict__ logt_p, const float* __restrict__ bias_p) {
  const int w = threadIdx.x >> 6, l = threadIdx.x & 63;
  const size_t row = (size_t)blockIdx.x * 4 + w;
  const float4* r4 = (const float4*)(in + row * DIM);
  float4 a = r4[l], b = r4[l + 64];
  float s = a.x*a.x + a.y*a.y + a.z*a.z + a.w*a.w
          + b.x*b.x + b.y*b.y + b.z*b.z + b.w*b.w;
#pragma unroll
  for (int off = 32; off; off >>= 1) s += __shfl_xor(s, off, 64);
  const float inv = 1.0f / (sqrtf(s) + 1e-12f);
  a.x *= inv; a.y *= inv; a.z *= inv; a.w *= inv;
  b.x *= inv; b.y *= inv; b.z *= inv; b.w *= inv;
  float4* o4 = (float4*)(outf + row * DIM);
  o4[l] = a; o4[l + 64] = b;
  int2 pa, pb;
  pa.x = (f2bf(a.x) & 0xFFFF) | ((int)f2bf(a.y) << 16);
  pa.y = (f2bf(a.z) & 0xFFFF) | ((int)f2bf(a.w) << 16);
  pb.x = (f2bf(b.x) & 0xFFFF) | ((int)f2bf(b.y) << 16);
  pb.y = (f2bf(b.z) & 0xFFFF) | ((int)f2bf(b.w) << 16);
  ((int2*)(outb + row * DIM))[l]       = pa;
  ((int2*)(outb + row * DIM + 256))[l] = pb;

  // fused true-positive logit (exact f32 path, identical to old tp_select)
  const int k = key[row];
  const float4* zt = (const float4*)(ztxt + (size_t)k * DIM);
  float4 c0 = zt[l], c1 = zt[l + 64];
  float d = a.x*c0.x + a.y*c0.y + a.z*c0.z + a.w*c0.w
          + b.x*c1.x + b.y*c1.y + b.z*c1.z + b.w*c1.w;
#pragma unroll
  for (int off = 32; off; off >>= 1) d += __shfl_xor(d, off, 64);
  if (l == 0) {
    const float t  = expf(logt_p[0]);
    const float tp = d * t + bias_p[0];
    const float loss = softplus_f(-tp);          // > 0 -> float bit order = value order
    const unsigned long long p =
        ((unsigned long long)__float_as_uint(loss) << 32) | (unsigned)row;
    atomicMin(&packed[k], p);                    // lexicographic (loss, index)
  }
}

// ---------------- select winners, gather bf16 rows (zero if no image) --------
__global__ __launch_bounds__(256) void gather_kernel(
    const unsigned long long* __restrict__ packed, float* __restrict__ out_idx,
    const short* __restrict__ zimgb, short* __restrict__ zselb) {
  const int w = threadIdx.x >> 6, l = threadIdx.x & 63;
  const int n = blockIdx.x * 4 + w;
  const unsigned long long p = packed[n];
  int4 v = {0, 0, 0, 0};
  float f = -1.0f;
  if (p != 0xFFFFFFFFFFFFFFFFull) {
    const int sel = (int)(p & 0xFFFFFFFFull);
    f = (float)sel;
    v = ((const int4*)(zimgb + (size_t)sel * DIM))[l];
  }
  ((int4*)(zselb + (size_t)n * DIM))[l] = v;
  if (l == 0) out_idx[n] = f;
}

// ---------------- merged bf16 MFMA GEMM, 256x256 tile, counted-vmcnt pipeline --
// blockIdx (remapped) by < 64 : C_ap = zimg * ztxt^T * t + b          (no loss)
//                     by >= 64: C_fl = zsel * ztxt^T * t + b, fused loss
// 8 waves (512 thr) as 2x4; per-wave output 128x64 -> acc[8][4] (128 VGPR).
// BK=32; 4-deep LDS ring buffer (4 x (16KB A + 16KB B) = 128 KiB) gives a
// 3-tile prefetch window: steady state waits s_waitcnt vmcnt(8) -- never 0 --
// via RAW s_barrier (NOT __syncthreads, which drains vmcnt(0)). Trailing
// lgkmcnt(0) per tile guarantees ds_reads completed before the ring slot is
// overwritten by the stage issued after the next barrier.
// XOR swizzle: 16B chunk ^= (row & 3), applied on the GLOBAL source side
// (global_load_lds dest must be lane-linear) and on the ds_read address.
// Balanced: each ds_read_b128 spreads 64 lanes 8-per-16B-slot-group.
__global__ __launch_bounds__(512, 2) void gemm_merged(
    const short* __restrict__ Aimg, const short* __restrict__ Asel,
    const short* __restrict__ B, float* __restrict__ Cap,
    float* __restrict__ Cfl, const float* __restrict__ logt_p,
    const float* __restrict__ bias_p, float* __restrict__ loss_out) {
  __shared__ alignas(16) short As[4][8192];   // 4 x 256x32 bf16 = 64 KiB
  __shared__ alignas(16) short Bs[4][8192];   // 64 KiB
  __shared__ float red[8];

  const int t  = threadIdx.x;
  const int w  = t >> 6, l = t & 63;
  const int wm = w >> 2, wn = w & 3;          // 2 x 4 wave grid
  const int fr = l & 15, quad = l >> 4;

  // XCD-aware bijective remap: 1280 blocks, 8 XCDs, 160/XCD, x-fastest chunk.
  int lin = blockIdx.y * 16 + blockIdx.x;
  lin = (lin & 7) * 160 + (lin >> 3);
  const int bx = lin & 15, by = lin >> 4;

  const bool fuse = (by >= 64);
  const int bm = (fuse ? by - 64 : by) << 8;
  const int bn = bx << 8;
  const short* A = fuse ? Asel : Aimg;
  float* C = fuse ? Cfl : Cap;

  // staging: thread t covers (row = t>>2 [+128 for site1], phys chunk = t&3);
  // global side reads logical chunk = (t&3) ^ (row&3)  (row&3 invariant +128)
  const int srow   = t >> 2;
  const int schunk = ((t & 3) ^ (srow & 3)) << 3;               // shorts
  const short* Ag = A + (size_t)(bm + srow) * KDIM + schunk;
  const short* Bg = B + (size_t)(bn + srow) * KDIM + schunk;
  const int sdst = w << 9;                                      // wave-uniform

  // ds_read side: logical chunk quad -> phys chunk quad ^ (fr&3)
  const int rchunk = (quad ^ (fr & 3)) << 3;                    // shorts
  const int abase = (wm * 128 + fr) * 32 + rchunk;
  const int bbase = (wn * 64 + fr) * 32 + rchunk;

  f32x4 acc[8][4] = {};

  auto stage = [&](int tile) {
    const int p = tile & 3;
    const int k0 = tile << 5;                                   // shorts
    const short* ga = Ag + k0;
    const short* gb = Bg + k0;
    short* la = &As[p][sdst];
    short* lb = &Bs[p][sdst];
    __builtin_amdgcn_global_load_lds(
        (const __attribute__((address_space(1))) void*)ga,
        (__attribute__((address_space(3))) void*)la, 16, 0, 0);
    __builtin_amdgcn_global_load_lds(
        (const __attribute__((address_space(1))) void*)(ga + (size_t)128 * KDIM),
        (__attribute__((address_space(3))) void*)(la + 4096), 16, 0, 0);
    __builtin_amdgcn_global_load_lds(
        (const __attribute__((address_space(1))) void*)gb,
        (__attribute__((address_space(3))) void*)lb, 16, 0, 0);
    __builtin_amdgcn_global_load_lds(
        (const __attribute__((address_space(1))) void*)(gb + (size_t)128 * KDIM),
        (__attribute__((address_space(3))) void*)(lb + 4096), 16, 0, 0);
  };

  // prologue: 3 tiles (12 loads/wave) in flight
  stage(0); stage(1); stage(2);

  // Ledger (per wave, 4 loads/tile): enter tile T with {T,T+1,T+2} in flight
  // (12); vmcnt(8) drains exactly tile T; stage(T+3) refills to 12.
  // Tail: T=14 enters with 8 -> vmcnt(4); T=15 enters with 4 -> vmcnt(0).
#define TILE(T, WN)                                                           \
  {                                                                           \
    asm volatile("s_waitcnt vmcnt(" #WN ")" ::: "memory");                    \
    __builtin_amdgcn_s_barrier();                                             \
    if ((T) + 3 < 16) stage((T) + 3);                                         \
    const short* Ab = &As[(T) & 3][abase];                                    \
    const short* Bb = &Bs[(T) & 3][bbase];                                    \
    bf16x8 af[8], bq[4];                                                      \
    _Pragma("unroll")                                                         \
    for (int mi = 0; mi < 8; ++mi) af[mi] = *(const bf16x8*)(Ab + mi * 512);  \
    _Pragma("unroll")                                                         \
    for (int nj = 0; nj < 4; ++nj) bq[nj] = *(const bf16x8*)(Bb + nj * 512);  \
    __builtin_amdgcn_s_setprio(1);                                            \
    _Pragma("unroll")                                                         \
    for (int mi = 0; mi < 8; ++mi)                                            \
      _Pragma("unroll")                                                       \
      for (int nj = 0; nj < 4; ++nj)                                          \
        acc[mi][nj] = __builtin_amdgcn_mfma_f32_16x16x32_bf16(                \
            af[mi], bq[nj], acc[mi][nj], 0, 0, 0);                            \
    __builtin_amdgcn_s_setprio(0);                                            \
    asm volatile("s_waitcnt lgkmcnt(0)" ::: "memory");                        \
  }

#pragma unroll
  for (int T = 0; T < 14; ++T) TILE(T, 8)
  TILE(14, 4)
  TILE(15, 0)
#undef TILE

  const float tt = expf(logt_p[0]);
  const float bb = bias_p[0];
  float lsum = 0.0f;
#pragma unroll
  for (int mi = 0; mi < 8; ++mi) {
#pragma unroll
    for (int nj = 0; nj < 4; ++nj) {
      const int grow0 = bm + wm * 128 + mi * 16 + quad * 4;
      const int gcol  = bn + wn * 64 + nj * 16 + fr;
      f32x4 a = acc[mi][nj];
#pragma unroll
      for (int r = 0; r < 4; ++r) {
        const float v = a[r] * tt + bb;
        __builtin_nontemporal_store(v, &C[(size_t)(grow0 + r) * N_TXT + gcol]);
        if (fuse) {
          const float lab = (grow0 + r == gcol) ? 1.0f : -1.0f;
          lsum += softplus_f(-lab * v);
        }
      }
    }
  }
  if (fuse) {
#pragma unroll
    for (int off = 32; off; off >>= 1) lsum += __shfl_xor(lsum, off, 64);
    if (l == 0) red[w] = lsum;
    __syncthreads();
    if (t == 0) {
      float s2 = 0.0f;
#pragma unroll
      for (int i = 0; i < 8; ++i) s2 += red[i];
      atomicAdd(loss_out, s2 * (1.0f / N_TXT));
    }
  }
}

// ---------------- launch --------------------------------------------------------
extern "C" void kernel_launch(void* const* d_in, const int* in_sizes, int n_in,
                              void* d_out, int out_size, void* d_ws, size_t ws_size,
                              hipStream_t stream) {
  const float* img  = (const float*)d_in[0];
  const float* txt  = (const float*)d_in[1];
  const int*   key  = (const int*)d_in[2];
  const float* logt = (const float*)d_in[3];
  const float* bias = (const float*)d_in[4];

  float* out    = (float*)d_out;
  float* o_loss = out;                                   // [1]
  float* o_sel  = out + 1;                               // [N]
  float* o_zimg = o_sel + N_TXT;                         // [S, 512]
  float* o_ztxt = o_zimg + (size_t)S_IMG * DIM;          // [N, 512]
  float* o_ap   = o_ztxt + (size_t)N_TXT * DIM;          // [S, N]
  float* o_fl   = o_ap + (size_t)S_IMG * N_TXT;          // [N, N]

  char* ws = (char*)d_ws;
  short* zimgb = (short*)ws;                                         // 16 MB
  short* ztxtb = (short*)(ws + (size_t)S_IMG * DIM * 2);             //  4 MB
  short* zselb = (short*)(ws + (size_t)(S_IMG + N_TXT) * DIM * 2);   //  4 MB
  unsigned long long* packed =
      (unsigned long long*)(ws + (size_t)(S_IMG + 2 * N_TXT) * DIM * 2);

  init_kernel<<<N_TXT / 256, 256, 0, stream>>>(packed, o_loss);
  normalize_kernel<<<N_TXT / 4, 256, 0, stream>>>(txt, o_ztxt, ztxtb);
  normalize_img_tp_kernel<<<S_IMG / 4, 256, 0, stream>>>(
      img, o_zimg, zimgb, o_ztxt, key, packed, logt, bias);
  gather_kernel<<<N_TXT / 4, 256, 0, stream>>>(packed, o_sel, zimgb, zselb);
  gemm_merged<<<dim3(N_TXT / 256, S_IMG / 256 + N_TXT / 256), 512, 0, stream>>>(
      zimgb, zselb, ztxtb, o_ap, o_fl, logt, bias, o_loss);
}